// Round 21
// baseline (78.888 us; speedup 1.0000x reference)
//
#include <hip/hip_runtime.h>

typedef __attribute__((ext_vector_type(4))) float  f32x4;
typedef __attribute__((ext_vector_type(2))) float  f32x2;
typedef __attribute__((ext_vector_type(8))) short  bf16x8;
typedef __attribute__((ext_vector_type(4))) unsigned int u32x4;

#define MFMA16(a,b,c) __builtin_amdgcn_mfma_f32_16x16x32_bf16(a,b,c,0,0,0)
#define SCL   0.360673760f   /* 0.25*log2(e) */
#define PBIAS 17.3123405f    /* fixed exp bias; epilogue sum-normalize -> exact softmax */

static __device__ __forceinline__ unsigned short f2bf(float f){
  unsigned int u = __float_as_uint(f);
  u += 0x7fffu + ((u>>16)&1u);
  return (unsigned short)(u>>16);
}
static __device__ __forceinline__ unsigned int pk2(float a, float b){
  return (unsigned)f2bf(a) | (((unsigned)f2bf(b))<<16);
}
static __device__ __forceinline__ float expfast(float a){   // 2^a, bare v_exp_f32
  float e; asm("v_exp_f32 %0, %1" : "=v"(e) : "v"(a)); return e;
}
static __device__ __forceinline__ f32x2 pkfma(f32x2 a, f32x2 b, f32x2 c){ // a*b+c packed
  f32x2 d; asm("v_pk_fma_f32 %0, %1, %2, %3" : "=v"(d) : "v"(a), "v"(b), "v"(c)); return d;
}
static __device__ __forceinline__ f32x2 pkadd(f32x2 a, f32x2 b){
  f32x2 d; asm("v_pk_add_f32 %0, %1, %2" : "=v"(d) : "v"(a), "v"(b)); return d;
}

// ---------------------------------------------------------------------------
// prep: q,k = x @ w^T + b (bf16), and xpk = bf16(x) packed in PV-B-frag order:
// xpk[(b*64+T)][F][lane(g,li)] (16B) = X[d=16F+li][kv=32T+8g..+7]
// grid 256 x 256; block = 64 s-rows.
// ---------------------------------------------------------------------------
__global__ __launch_bounds__(256,2) void prep_kernel(
    const float* __restrict__ x,  const float* __restrict__ wq, const float* __restrict__ bq,
    const float* __restrict__ wk, const float* __restrict__ bk,
    unsigned short* __restrict__ qws, unsigned short* __restrict__ kws,
    unsigned char* __restrict__ xpk)
{
  __shared__ __align__(16) unsigned short wlds[32*1032];
  __shared__ __align__(16) unsigned short xlds[64*72];
  const int t  = threadIdx.x;
  const int r0 = blockIdx.x<<6;
  const int b  = r0>>11;
  const int s0 = r0&2047;
  const int l = t&63, w = t>>6, g = l>>4, li = l&15;

  { const int n = t>>3, part = t&7;
    const float* wsrc = (n<16) ? (wq + n*1024) : (wk + (n-16)*1024);
    #pragma unroll
    for(int cc=0; cc<16; ++cc){
      const int d = part*128 + cc*8;
      f32x4 f0 = *(const f32x4*)(wsrc + d);
      f32x4 f1 = *(const f32x4*)(wsrc + d + 4);
      u32x4 p;
      p[0]=pk2(f0[0],f0[1]); p[1]=pk2(f0[2],f0[3]);
      p[2]=pk2(f1[0],f1[1]); p[3]=pk2(f1[2],f1[3]);
      *(u32x4*)(&wlds[n*1032 + d]) = p;
    }
  }
  __syncthreads();

  f32x4 acc0 = {0.f,0.f,0.f,0.f};
  f32x4 acc1 = {0.f,0.f,0.f,0.f};
  const int srow = t>>2, dch = t&3;   // staging roles
  const int dd = t&63, sch = t>>6;    // pack roles: column dd, s-chunk sch*16..+15

  // pack destination: T = s0/32 + sch/2, F = it*4 + dd/16
  unsigned char* pdst = xpk + ((size_t)(b*64 + (s0>>5) + (sch>>1)))*65536
                      + (size_t)(dd>>4)*1024 + (size_t)(sch&1)*512 + (size_t)(dd&15)*16;

  for(int it=0; it<16; ++it){
    { const float* xp = x + (size_t)(r0+srow)*1024 + it*64 + dch*16;
      f32x4 a0 = *(const f32x4*)(xp);
      f32x4 a1 = *(const f32x4*)(xp+4);
      f32x4 a2 = *(const f32x4*)(xp+8);
      f32x4 a3 = *(const f32x4*)(xp+12);
      u32x4 p0, p1;
      p0[0]=pk2(a0[0],a0[1]); p0[1]=pk2(a0[2],a0[3]);
      p0[2]=pk2(a1[0],a1[1]); p0[3]=pk2(a1[2],a1[3]);
      p1[0]=pk2(a2[0],a2[1]); p1[1]=pk2(a2[2],a2[3]);
      p1[2]=pk2(a3[0],a3[1]); p1[3]=pk2(a3[2],a3[3]);
      *(u32x4*)(&xlds[srow*72 + dch*16])     = p0;
      *(u32x4*)(&xlds[srow*72 + dch*16 + 8]) = p1;
    }
    __syncthreads();
    #pragma unroll
    for(int ks=0; ks<2; ++ks){
      bf16x8 a  = *(const bf16x8*)(&xlds[(16*w+li)*72       + ks*32 + g*8]);
      bf16x8 b0 = *(const bf16x8*)(&wlds[ li*1032     + it*64 + ks*32 + g*8]);
      bf16x8 b1 = *(const bf16x8*)(&wlds[(16+li)*1032 + it*64 + ks*32 + g*8]);
      acc0 = MFMA16(a,b0,acc0);
      acc1 = MFMA16(a,b1,acc1);
    }
    { // pack-write: thread owns column dd, s-range 16sch..+15 (= kv-runs of 8)
      unsigned short v[16];
      #pragma unroll
      for(int jj=0; jj<16; ++jj) v[jj] = xlds[(sch*16 + jj)*72 + dd];
      u32x4 o0, o1;
      o0[0]=(unsigned)v[0]|((unsigned)v[1]<<16);   o0[1]=(unsigned)v[2]|((unsigned)v[3]<<16);
      o0[2]=(unsigned)v[4]|((unsigned)v[5]<<16);   o0[3]=(unsigned)v[6]|((unsigned)v[7]<<16);
      o1[0]=(unsigned)v[8]|((unsigned)v[9]<<16);   o1[1]=(unsigned)v[10]|((unsigned)v[11]<<16);
      o1[2]=(unsigned)v[12]|((unsigned)v[13]<<16); o1[3]=(unsigned)v[14]|((unsigned)v[15]<<16);
      unsigned char* dst = pdst + (size_t)it*4096;
      *(u32x4*)(dst)       = o0;   // g = (sch&1)*2
      *(u32x4*)(dst + 256) = o1;   // g+1
    }
    __syncthreads();
  }
  #pragma unroll
  for(int reg=0; reg<4; ++reg){
    const int sr = r0 + 16*w + 4*g + reg;
    qws[(size_t)sr*16 + li] = f2bf(acc0[reg] + bq[li]);
    kws[(size_t)sr*16 + li] = f2bf(acc1[reg] + bk[li]);
  }
}

// ---------------------------------------------------------------------------
// attn v21 = v15b (verified) + balanced co-residency mapping (v10's bijective
// j->(qb,dq) map, now at the correct (256,3) occupancy): co-resident CU slots
// {j, j+32, j+64, j+96} cover dq 0..3 with qb sums == 62 -> uniform ~66
// tiles/CU, smaller ragged tail. Data path byte-identical to v15b:
// KVBLK=64; frag-packed coalesced X (same-iter issue->PV use); K prefetch 1
// tile; packed-math exp path; dbuf P-share; ONE raw s_barrier/tile.
// ---------------------------------------------------------------------------
__global__ __launch_bounds__(256,3) void attn_kernel(
    const unsigned short* __restrict__ qws, const unsigned short* __restrict__ kws,
    const unsigned char* __restrict__ xpk, float* __restrict__ out)
{
  __shared__ __align__(16) unsigned char pshare[16384];  // [2 buf][4 qf][2 half][64 lanes][16B]
  __shared__ float psL[64];
  const int t = threadIdx.x;
  const int l = t&63, w = t>>6, g = l>>4, li = l&15;
  const int bi = blockIdx.x;
  const int b = bi&7;                  // XCD batch affinity
  const int j = bi>>3;                 // 0..127
  const int m = j&31, rr = j>>5;
  int qb;
  if(rr==0)      qb = 31-m;
  else if(rr==1) qb = m;
  else if(rr==2) qb = (m<16) ? 15-m : 47-m;
  else           qb = (m+16)&31;       // bijective; per-CU-slot qb sums = 62
  const int dq = rr;
  const int q0 = qb<<6, d0 = dq<<8, nt = qb + 1;

  // K-row permutation: S-MFMA C-row r <-> kv 8*(r>>2)+(r&3)
  const int kperm = ((li>>2)<<3) + (li&3);

  const bf16x8 zero8 = {0,0,0,0,0,0,0,0};
  bf16x8 qfr = zero8;                  // own S q-slice: qf = w
  if(g < 2) qfr = *(const bf16x8*)(qws + ((size_t)(b*2048 + q0 + 16*w + li)<<4) + 8*g);
  const int qg = q0 + 16*w + li;

  f32x4 acc[4][4];
  #pragma unroll
  for(int i=0;i<4;++i)
    #pragma unroll
    for(int jj=0;jj<4;++jj){ acc[i][jj][0]=0.f; acc[i][jj][1]=0.f; acc[i][jj][2]=0.f; acc[i][jj][3]=0.f; }
  f32x2 spv = {0.f, 0.f};              // deferred row-sum accumulator

  // packed X: frag df of 32-kv tile T at xq + T*65536 + df*1024, lane off l*16
  const unsigned char* xq = xpk + (size_t)(b*64)*65536 + (size_t)(16*dq + 4*w)*1024 + l*16;
  const unsigned short* kp0 = kws + ((size_t)(b*2048 + kperm)<<4) + 8*g;

  // prologue: K(0)  (all lanes load; g>=2 content is don't-care since qfr==0)
  bf16x8 k1 = *(const bf16x8*)(kp0);
  bf16x8 k2 = *(const bf16x8*)(kp0 + 64);
  bf16x8 k3 = *(const bf16x8*)(kp0 + 512);
  bf16x8 k4 = *(const bf16x8*)(kp0 + 576);

  const f32x2 vscl = {SCL, SCL}, vbias = {-PBIAS, -PBIAS};

  int buf = 0;
  for(int tt=0; tt<nt; ++tt){
    const int kv0 = tt<<6;
    // ---- X loads for THIS tile (coalesced 1KB each; consumed in PV below,
    //      ~400cy later: S + exp + cvt + barrier hide the latency) ----
    u32x4 xc[4], xd[4];
    const unsigned char* xqt = xq + (size_t)(tt*2)*65536;
    #pragma unroll
    for(int df=0; df<4; ++df){
      xc[df] = *(const u32x4*)(xqt + df*1024);
      xd[df] = *(const u32x4*)(xqt + 65536 + df*1024);
    }
    // ---- S: own 16q x 64kv ----
    f32x4 z = {0.f,0.f,0.f,0.f};
    f32x4 s1 = MFMA16(k1, qfr, z);   // kv0 + 8g+0..3
    f32x4 s2 = MFMA16(k2, qfr, z);   // kv0 + 8g+4..7
    f32x4 s3 = MFMA16(k3, qfr, z);   // kv0+32 + 8g+0..3
    f32x4 s4 = MFMA16(k4, qfr, z);   // kv0+32 + 8g+4..7
    // ---- K prefetch (tt+1; consumed at next iter's S) ----
    const int tn = (tt+1 < nt) ? tt+1 : tt;
    const unsigned short* kpn = kp0 + (size_t)(tn<<6)*16;
    bf16x8 n1 = *(const bf16x8*)(kpn);
    bf16x8 n2 = *(const bf16x8*)(kpn + 64);
    bf16x8 n3 = *(const bf16x8*)(kpn + 512);
    bf16x8 n4 = *(const bf16x8*)(kpn + 576);
    // ---- exp path: packed scale/bias, scalar v_exp, packed sum tree ----
    f32x2 e[8];
    if(tt < nt-1){
      f32x2 tv[8];
      tv[0] = pkfma((f32x2){s1[0], s1[1]}, vscl, vbias);
      tv[1] = pkfma((f32x2){s1[2], s1[3]}, vscl, vbias);
      tv[2] = pkfma((f32x2){s2[0], s2[1]}, vscl, vbias);
      tv[3] = pkfma((f32x2){s2[2], s2[3]}, vscl, vbias);
      tv[4] = pkfma((f32x2){s3[0], s3[1]}, vscl, vbias);
      tv[5] = pkfma((f32x2){s3[2], s3[3]}, vscl, vbias);
      tv[6] = pkfma((f32x2){s4[0], s4[1]}, vscl, vbias);
      tv[7] = pkfma((f32x2){s4[2], s4[3]}, vscl, vbias);
      #pragma unroll
      for(int i=0;i<8;++i){ e[i][0] = expfast(tv[i][0]); e[i][1] = expfast(tv[i][1]); }
    } else {
      const int b1 = kv0 + 8*g, b2 = kv0 + 32 + 8*g;
      float p[16];
      #pragma unroll
      for(int r=0;r<4;++r){
        p[r]    = (b1+r   <= qg) ? expfast(fmaf(s1[r], SCL, -PBIAS)) : 0.f;
        p[4+r]  = (b1+4+r <= qg) ? expfast(fmaf(s2[r], SCL, -PBIAS)) : 0.f;
        p[8+r]  = (b2+r   <= qg) ? expfast(fmaf(s3[r], SCL, -PBIAS)) : 0.f;
        p[12+r] = (b2+4+r <= qg) ? expfast(fmaf(s4[r], SCL, -PBIAS)) : 0.f;
      }
      #pragma unroll
      for(int i=0;i<8;++i){ e[i][0] = p[2*i]; e[i][1] = p[2*i+1]; }
    }
    { // packed sum tree into deferred accumulator
      f32x2 a0 = pkadd(e[0], e[1]);
      f32x2 a1 = pkadd(e[2], e[3]);
      f32x2 a2 = pkadd(e[4], e[5]);
      f32x2 a3 = pkadd(e[6], e[7]);
      spv = pkadd(spv, pkadd(pkadd(a0,a1), pkadd(a2,a3)));
    }
    { u32x4 avA, avB;
      asm("v_cvt_pk_bf16_f32 %0, %1, %2" : "=v"(avA[0]) : "v"(e[0][0]), "v"(e[0][1]));
      asm("v_cvt_pk_bf16_f32 %0, %1, %2" : "=v"(avA[1]) : "v"(e[1][0]), "v"(e[1][1]));
      asm("v_cvt_pk_bf16_f32 %0, %1, %2" : "=v"(avA[2]) : "v"(e[2][0]), "v"(e[2][1]));
      asm("v_cvt_pk_bf16_f32 %0, %1, %2" : "=v"(avA[3]) : "v"(e[3][0]), "v"(e[3][1]));
      asm("v_cvt_pk_bf16_f32 %0, %1, %2" : "=v"(avB[0]) : "v"(e[4][0]), "v"(e[4][1]));
      asm("v_cvt_pk_bf16_f32 %0, %1, %2" : "=v"(avB[1]) : "v"(e[5][0]), "v"(e[5][1]));
      asm("v_cvt_pk_bf16_f32 %0, %1, %2" : "=v"(avB[2]) : "v"(e[6][0]), "v"(e[6][1]));
      asm("v_cvt_pk_bf16_f32 %0, %1, %2" : "=v"(avB[3]) : "v"(e[7][0]), "v"(e[7][1]));
      *(u32x4*)(&pshare[buf*8192 + w*2048 +        l*16]) = avA;
      *(u32x4*)(&pshare[buf*8192 + w*2048 + 1024 + l*16]) = avB;
    }
    asm volatile("s_waitcnt lgkmcnt(0)" ::: "memory");   // P-write visible
    __builtin_amdgcn_sched_barrier(0);
    __builtin_amdgcn_s_barrier();                        // ONE barrier per tile
    __builtin_amdgcn_sched_barrier(0);
    // ---- PV: acc[qf][df] += P @ X  (32 MFMA) ----
    __builtin_amdgcn_s_setprio(1);
    #pragma unroll
    for(int qf=0; qf<4; ++qf){
      bf16x8 aA = *(const bf16x8*)(&pshare[buf*8192 + qf*2048 +        l*16]);
      bf16x8 aB = *(const bf16x8*)(&pshare[buf*8192 + qf*2048 + 1024 + l*16]);
      #pragma unroll
      for(int df=0; df<4; ++df){
        acc[qf][df] = MFMA16(aA, *(const bf16x8*)(&xc[df]), acc[qf][df]);
        acc[qf][df] = MFMA16(aB, *(const bf16x8*)(&xd[df]), acc[qf][df]);
      }
    }
    __builtin_amdgcn_s_setprio(0);
    buf ^= 1; k1=n1; k2=n2; k3=n3; k4=n4;
  }

  // ---- epilogue: share row sums, normalize, store ----
  float r_ = spv[0] + spv[1];
  r_ += __shfl_xor(r_, 16);
  r_ += __shfl_xor(r_, 32);
  if(l < 16) psL[16*w + l] = r_;
  __syncthreads();
  #pragma unroll
  for(int qf=0; qf<4; ++qf){
    const f32x4 pv = *(const f32x4*)(&psL[16*qf + 4*g]);
    #pragma unroll
    for(int reg=0; reg<4; ++reg){
      const float inv = 1.0f/pv[reg];
      float* op = out + (size_t)(b*2048 + q0 + 16*qf + 4*g + reg)*1024 + d0 + 64*w + li;
      #pragma unroll
      for(int df=0; df<4; ++df) op[df*16] = acc[qf][df][reg]*inv;
    }
  }
}

// ---------------------------------------------------------------------------
extern "C" void kernel_launch(void* const* d_in, const int* in_sizes, int n_in,
                              void* d_out, int out_size, void* d_ws, size_t ws_size,
                              hipStream_t stream) {
  (void)in_sizes; (void)n_in; (void)out_size; (void)ws_size;
  const float* x  = (const float*)d_in[0];
  const float* wq = (const float*)d_in[1];
  const float* bq = (const float*)d_in[2];
  const float* wk = (const float*)d_in[3];
  const float* bk = (const float*)d_in[4];
  float* out = (float*)d_out;
  char* ws = (char*)d_ws;
  unsigned short* qws = (unsigned short*)(ws);             // 512KB  [8*2048][16] bf16
  unsigned short* kws = (unsigned short*)(ws + (512<<10)); // 512KB
  unsigned char*  xpk = (unsigned char*)(ws + (2<<20));    // 33.5MB frag-packed X
  hipLaunchKernelGGL(prep_kernel, dim3(256), dim3(256), 0, stream, x, wq, bq, wk, bk, qws, kws, xpk);
  hipLaunchKernelGGL(attn_kernel, dim3(1024), dim3(256), 0, stream, qws, kws, xpk, out);
}

// Round 22
// 68.623 us; speedup vs baseline: 1.1496x; 1.1496x over previous
//
#include <hip/hip_runtime.h>

typedef __attribute__((ext_vector_type(4))) float  f32x4;
typedef __attribute__((ext_vector_type(2))) float  f32x2;
typedef __attribute__((ext_vector_type(8))) short  bf16x8;
typedef __attribute__((ext_vector_type(4))) unsigned int u32x4;

#define MFMA16(a,b,c) __builtin_amdgcn_mfma_f32_16x16x32_bf16(a,b,c,0,0,0)
#define SCL   0.360673760f   /* 0.25*log2(e) */
#define PBIAS 17.3123405f    /* fixed exp bias; epilogue sum-normalize -> exact softmax */

static __device__ __forceinline__ unsigned short f2bf(float f){
  unsigned int u = __float_as_uint(f);
  u += 0x7fffu + ((u>>16)&1u);
  return (unsigned short)(u>>16);
}
static __device__ __forceinline__ unsigned int pk2(float a, float b){
  return (unsigned)f2bf(a) | (((unsigned)f2bf(b))<<16);
}
static __device__ __forceinline__ float expfast(float a){   // 2^a, bare v_exp_f32
  float e; asm("v_exp_f32 %0, %1" : "=v"(e) : "v"(a)); return e;
}
static __device__ __forceinline__ f32x2 pkfma(f32x2 a, f32x2 b, f32x2 c){ // a*b+c packed
  f32x2 d; asm("v_pk_fma_f32 %0, %1, %2, %3" : "=v"(d) : "v"(a), "v"(b), "v"(c)); return d;
}
static __device__ __forceinline__ f32x2 pkadd(f32x2 a, f32x2 b){
  f32x2 d; asm("v_pk_add_f32 %0, %1, %2" : "=v"(d) : "v"(a), "v"(b)); return d;
}

// ---------------------------------------------------------------------------
// prep: q,k = x @ w^T + b (bf16), and xpk = bf16(x) packed in PV-B-frag order:
// xpk[(b*64+T)][F][lane(g,li)] (16B) = X[d=16F+li][kv=32T+8g..+7]
// grid 256 x 256; block = 64 s-rows.
// ---------------------------------------------------------------------------
__global__ __launch_bounds__(256,2) void prep_kernel(
    const float* __restrict__ x,  const float* __restrict__ wq, const float* __restrict__ bq,
    const float* __restrict__ wk, const float* __restrict__ bk,
    unsigned short* __restrict__ qws, unsigned short* __restrict__ kws,
    unsigned char* __restrict__ xpk)
{
  __shared__ __align__(16) unsigned short wlds[32*1032];
  __shared__ __align__(16) unsigned short xlds[64*72];
  const int t  = threadIdx.x;
  const int r0 = blockIdx.x<<6;
  const int b  = r0>>11;
  const int s0 = r0&2047;
  const int l = t&63, w = t>>6, g = l>>4, li = l&15;

  { const int n = t>>3, part = t&7;
    const float* wsrc = (n<16) ? (wq + n*1024) : (wk + (n-16)*1024);
    #pragma unroll
    for(int cc=0; cc<16; ++cc){
      const int d = part*128 + cc*8;
      f32x4 f0 = *(const f32x4*)(wsrc + d);
      f32x4 f1 = *(const f32x4*)(wsrc + d + 4);
      u32x4 p;
      p[0]=pk2(f0[0],f0[1]); p[1]=pk2(f0[2],f0[3]);
      p[2]=pk2(f1[0],f1[1]); p[3]=pk2(f1[2],f1[3]);
      *(u32x4*)(&wlds[n*1032 + d]) = p;
    }
  }
  __syncthreads();

  f32x4 acc0 = {0.f,0.f,0.f,0.f};
  f32x4 acc1 = {0.f,0.f,0.f,0.f};
  const int srow = t>>2, dch = t&3;   // staging roles
  const int dd = t&63, sch = t>>6;    // pack roles: column dd, s-chunk sch*16..+15

  // pack destination: T = s0/32 + sch/2, F = it*4 + dd/16
  unsigned char* pdst = xpk + ((size_t)(b*64 + (s0>>5) + (sch>>1)))*65536
                      + (size_t)(dd>>4)*1024 + (size_t)(sch&1)*512 + (size_t)(dd&15)*16;

  for(int it=0; it<16; ++it){
    { const float* xp = x + (size_t)(r0+srow)*1024 + it*64 + dch*16;
      f32x4 a0 = *(const f32x4*)(xp);
      f32x4 a1 = *(const f32x4*)(xp+4);
      f32x4 a2 = *(const f32x4*)(xp+8);
      f32x4 a3 = *(const f32x4*)(xp+12);
      u32x4 p0, p1;
      p0[0]=pk2(a0[0],a0[1]); p0[1]=pk2(a0[2],a0[3]);
      p0[2]=pk2(a1[0],a1[1]); p0[3]=pk2(a1[2],a1[3]);
      p1[0]=pk2(a2[0],a2[1]); p1[1]=pk2(a2[2],a2[3]);
      p1[2]=pk2(a3[0],a3[1]); p1[3]=pk2(a3[2],a3[3]);
      *(u32x4*)(&xlds[srow*72 + dch*16])     = p0;
      *(u32x4*)(&xlds[srow*72 + dch*16 + 8]) = p1;
    }
    __syncthreads();
    #pragma unroll
    for(int ks=0; ks<2; ++ks){
      bf16x8 a  = *(const bf16x8*)(&xlds[(16*w+li)*72       + ks*32 + g*8]);
      bf16x8 b0 = *(const bf16x8*)(&wlds[ li*1032     + it*64 + ks*32 + g*8]);
      bf16x8 b1 = *(const bf16x8*)(&wlds[(16+li)*1032 + it*64 + ks*32 + g*8]);
      acc0 = MFMA16(a,b0,acc0);
      acc1 = MFMA16(a,b1,acc1);
    }
    { // pack-write: thread owns column dd, s-range 16sch..+15 (= kv-runs of 8)
      unsigned short v[16];
      #pragma unroll
      for(int jj=0; jj<16; ++jj) v[jj] = xlds[(sch*16 + jj)*72 + dd];
      u32x4 o0, o1;
      o0[0]=(unsigned)v[0]|((unsigned)v[1]<<16);   o0[1]=(unsigned)v[2]|((unsigned)v[3]<<16);
      o0[2]=(unsigned)v[4]|((unsigned)v[5]<<16);   o0[3]=(unsigned)v[6]|((unsigned)v[7]<<16);
      o1[0]=(unsigned)v[8]|((unsigned)v[9]<<16);   o1[1]=(unsigned)v[10]|((unsigned)v[11]<<16);
      o1[2]=(unsigned)v[12]|((unsigned)v[13]<<16); o1[3]=(unsigned)v[14]|((unsigned)v[15]<<16);
      unsigned char* dst = pdst + (size_t)it*4096;
      *(u32x4*)(dst)       = o0;   // g = (sch&1)*2
      *(u32x4*)(dst + 256) = o1;   // g+1
    }
    __syncthreads();
  }
  #pragma unroll
  for(int reg=0; reg<4; ++reg){
    const int sr = r0 + 16*w + 4*g + reg;
    qws[(size_t)sr*16 + li] = f2bf(acc0[reg] + bq[li]);
    kws[(size_t)sr*16 + li] = f2bf(acc1[reg] + bk[li]);
  }
}

// ---------------------------------------------------------------------------
// attn v15b (final, verified): block = (b, 64-q, 256-d quarter); 4 waves;
// KVBLK=64; frag-packed coalesced X (same-iter issue->PV use); K prefetch 1
// tile; packed-math exp path; dbuf P-share; ONE raw s_barrier/tile; (256,3);
// LPT grid 1024 (big-qb-first dispatch -- beats static balance, r21).
// ---------------------------------------------------------------------------
__global__ __launch_bounds__(256,3) void attn_kernel(
    const unsigned short* __restrict__ qws, const unsigned short* __restrict__ kws,
    const unsigned char* __restrict__ xpk, float* __restrict__ out)
{
  __shared__ __align__(16) unsigned char pshare[16384];  // [2 buf][4 qf][2 half][64 lanes][16B]
  __shared__ float psL[64];
  const int t = threadIdx.x;
  const int l = t&63, w = t>>6, g = l>>4, li = l&15;
  const int bi = blockIdx.x;
  const int b = bi&7;                  // XCD batch affinity
  const int j = bi>>3;
  const int qb = 31-(j>>2), dq = j&3;  // LPT: big q-blocks first
  const int q0 = qb<<6, d0 = dq<<8, nt = qb + 1;

  // K-row permutation: S-MFMA C-row r <-> kv 8*(r>>2)+(r&3)
  const int kperm = ((li>>2)<<3) + (li&3);

  const bf16x8 zero8 = {0,0,0,0,0,0,0,0};
  bf16x8 qfr = zero8;                  // own S q-slice: qf = w
  if(g < 2) qfr = *(const bf16x8*)(qws + ((size_t)(b*2048 + q0 + 16*w + li)<<4) + 8*g);
  const int qg = q0 + 16*w + li;

  f32x4 acc[4][4];
  #pragma unroll
  for(int i=0;i<4;++i)
    #pragma unroll
    for(int jj=0;jj<4;++jj){ acc[i][jj][0]=0.f; acc[i][jj][1]=0.f; acc[i][jj][2]=0.f; acc[i][jj][3]=0.f; }
  f32x2 spv = {0.f, 0.f};              // deferred row-sum accumulator

  // packed X: frag df of 32-kv tile T at xq + T*65536 + df*1024, lane off l*16
  const unsigned char* xq = xpk + (size_t)(b*64)*65536 + (size_t)(16*dq + 4*w)*1024 + l*16;
  const unsigned short* kp0 = kws + ((size_t)(b*2048 + kperm)<<4) + 8*g;

  // prologue: K(0)  (all lanes load; g>=2 content is don't-care since qfr==0)
  bf16x8 k1 = *(const bf16x8*)(kp0);
  bf16x8 k2 = *(const bf16x8*)(kp0 + 64);
  bf16x8 k3 = *(const bf16x8*)(kp0 + 512);
  bf16x8 k4 = *(const bf16x8*)(kp0 + 576);

  const f32x2 vscl = {SCL, SCL}, vbias = {-PBIAS, -PBIAS};

  int buf = 0;
  for(int tt=0; tt<nt; ++tt){
    const int kv0 = tt<<6;
    // ---- X loads for THIS tile (coalesced 1KB each; consumed in PV below,
    //      ~400cy later: S + exp + cvt + barrier hide the latency) ----
    u32x4 xc[4], xd[4];
    const unsigned char* xqt = xq + (size_t)(tt*2)*65536;
    #pragma unroll
    for(int df=0; df<4; ++df){
      xc[df] = *(const u32x4*)(xqt + df*1024);
      xd[df] = *(const u32x4*)(xqt + 65536 + df*1024);
    }
    // ---- S: own 16q x 64kv ----
    f32x4 z = {0.f,0.f,0.f,0.f};
    f32x4 s1 = MFMA16(k1, qfr, z);   // kv0 + 8g+0..3
    f32x4 s2 = MFMA16(k2, qfr, z);   // kv0 + 8g+4..7
    f32x4 s3 = MFMA16(k3, qfr, z);   // kv0+32 + 8g+0..3
    f32x4 s4 = MFMA16(k4, qfr, z);   // kv0+32 + 8g+4..7
    // ---- K prefetch (tt+1; consumed at next iter's S) ----
    const int tn = (tt+1 < nt) ? tt+1 : tt;
    const unsigned short* kpn = kp0 + (size_t)(tn<<6)*16;
    bf16x8 n1 = *(const bf16x8*)(kpn);
    bf16x8 n2 = *(const bf16x8*)(kpn + 64);
    bf16x8 n3 = *(const bf16x8*)(kpn + 512);
    bf16x8 n4 = *(const bf16x8*)(kpn + 576);
    // ---- exp path: packed scale/bias, scalar v_exp, packed sum tree ----
    f32x2 e[8];
    if(tt < nt-1){
      f32x2 tv[8];
      tv[0] = pkfma((f32x2){s1[0], s1[1]}, vscl, vbias);
      tv[1] = pkfma((f32x2){s1[2], s1[3]}, vscl, vbias);
      tv[2] = pkfma((f32x2){s2[0], s2[1]}, vscl, vbias);
      tv[3] = pkfma((f32x2){s2[2], s2[3]}, vscl, vbias);
      tv[4] = pkfma((f32x2){s3[0], s3[1]}, vscl, vbias);
      tv[5] = pkfma((f32x2){s3[2], s3[3]}, vscl, vbias);
      tv[6] = pkfma((f32x2){s4[0], s4[1]}, vscl, vbias);
      tv[7] = pkfma((f32x2){s4[2], s4[3]}, vscl, vbias);
      #pragma unroll
      for(int i=0;i<8;++i){ e[i][0] = expfast(tv[i][0]); e[i][1] = expfast(tv[i][1]); }
    } else {
      const int b1 = kv0 + 8*g, b2 = kv0 + 32 + 8*g;
      float p[16];
      #pragma unroll
      for(int r=0;r<4;++r){
        p[r]    = (b1+r   <= qg) ? expfast(fmaf(s1[r], SCL, -PBIAS)) : 0.f;
        p[4+r]  = (b1+4+r <= qg) ? expfast(fmaf(s2[r], SCL, -PBIAS)) : 0.f;
        p[8+r]  = (b2+r   <= qg) ? expfast(fmaf(s3[r], SCL, -PBIAS)) : 0.f;
        p[12+r] = (b2+4+r <= qg) ? expfast(fmaf(s4[r], SCL, -PBIAS)) : 0.f;
      }
      #pragma unroll
      for(int i=0;i<8;++i){ e[i][0] = p[2*i]; e[i][1] = p[2*i+1]; }
    }
    { // packed sum tree into deferred accumulator
      f32x2 a0 = pkadd(e[0], e[1]);
      f32x2 a1 = pkadd(e[2], e[3]);
      f32x2 a2 = pkadd(e[4], e[5]);
      f32x2 a3 = pkadd(e[6], e[7]);
      spv = pkadd(spv, pkadd(pkadd(a0,a1), pkadd(a2,a3)));
    }
    { u32x4 avA, avB;
      asm("v_cvt_pk_bf16_f32 %0, %1, %2" : "=v"(avA[0]) : "v"(e[0][0]), "v"(e[0][1]));
      asm("v_cvt_pk_bf16_f32 %0, %1, %2" : "=v"(avA[1]) : "v"(e[1][0]), "v"(e[1][1]));
      asm("v_cvt_pk_bf16_f32 %0, %1, %2" : "=v"(avA[2]) : "v"(e[2][0]), "v"(e[2][1]));
      asm("v_cvt_pk_bf16_f32 %0, %1, %2" : "=v"(avA[3]) : "v"(e[3][0]), "v"(e[3][1]));
      asm("v_cvt_pk_bf16_f32 %0, %1, %2" : "=v"(avB[0]) : "v"(e[4][0]), "v"(e[4][1]));
      asm("v_cvt_pk_bf16_f32 %0, %1, %2" : "=v"(avB[1]) : "v"(e[5][0]), "v"(e[5][1]));
      asm("v_cvt_pk_bf16_f32 %0, %1, %2" : "=v"(avB[2]) : "v"(e[6][0]), "v"(e[6][1]));
      asm("v_cvt_pk_bf16_f32 %0, %1, %2" : "=v"(avB[3]) : "v"(e[7][0]), "v"(e[7][1]));
      *(u32x4*)(&pshare[buf*8192 + w*2048 +        l*16]) = avA;
      *(u32x4*)(&pshare[buf*8192 + w*2048 + 1024 + l*16]) = avB;
    }
    asm volatile("s_waitcnt lgkmcnt(0)" ::: "memory");   // P-write visible
    __builtin_amdgcn_sched_barrier(0);
    __builtin_amdgcn_s_barrier();                        // ONE barrier per tile
    __builtin_amdgcn_sched_barrier(0);
    // ---- PV: acc[qf][df] += P @ X  (32 MFMA) ----
    __builtin_amdgcn_s_setprio(1);
    #pragma unroll
    for(int qf=0; qf<4; ++qf){
      bf16x8 aA = *(const bf16x8*)(&pshare[buf*8192 + qf*2048 +        l*16]);
      bf16x8 aB = *(const bf16x8*)(&pshare[buf*8192 + qf*2048 + 1024 + l*16]);
      #pragma unroll
      for(int df=0; df<4; ++df){
        acc[qf][df] = MFMA16(aA, *(const bf16x8*)(&xc[df]), acc[qf][df]);
        acc[qf][df] = MFMA16(aB, *(const bf16x8*)(&xd[df]), acc[qf][df]);
      }
    }
    __builtin_amdgcn_s_setprio(0);
    buf ^= 1; k1=n1; k2=n2; k3=n3; k4=n4;
  }

  // ---- epilogue: share row sums, normalize, store ----
  float r_ = spv[0] + spv[1];
  r_ += __shfl_xor(r_, 16);
  r_ += __shfl_xor(r_, 32);
  if(l < 16) psL[16*w + l] = r_;
  __syncthreads();
  #pragma unroll
  for(int qf=0; qf<4; ++qf){
    const f32x4 pv = *(const f32x4*)(&psL[16*qf + 4*g]);
    #pragma unroll
    for(int reg=0; reg<4; ++reg){
      const float inv = 1.0f/pv[reg];
      float* op = out + (size_t)(b*2048 + q0 + 16*qf + 4*g + reg)*1024 + d0 + 64*w + li;
      #pragma unroll
      for(int df=0; df<4; ++df) op[df*16] = acc[qf][df][reg]*inv;
    }
  }
}

// ---------------------------------------------------------------------------
extern "C" void kernel_launch(void* const* d_in, const int* in_sizes, int n_in,
                              void* d_out, int out_size, void* d_ws, size_t ws_size,
                              hipStream_t stream) {
  (void)in_sizes; (void)n_in; (void)out_size; (void)ws_size;
  const float* x  = (const float*)d_in[0];
  const float* wq = (const float*)d_in[1];
  const float* bq = (const float*)d_in[2];
  const float* wk = (const float*)d_in[3];
  const float* bk = (const float*)d_in[4];
  float* out = (float*)d_out;
  char* ws = (char*)d_ws;
  unsigned short* qws = (unsigned short*)(ws);             // 512KB  [8*2048][16] bf16
  unsigned short* kws = (unsigned short*)(ws + (512<<10)); // 512KB
  unsigned char*  xpk = (unsigned char*)(ws + (2<<20));    // 33.5MB frag-packed X
  hipLaunchKernelGGL(prep_kernel, dim3(256), dim3(256), 0, stream, x, wq, bq, wk, bk, qws, kws, xpk);
  hipLaunchKernelGGL(attn_kernel, dim3(1024), dim3(256), 0, stream, qws, kws, xpk, out);
}